// Round 1
// baseline (282.608 us; speedup 1.0000x reference)
//
#include <hip/hip_runtime.h>
#include <hip/hip_bf16.h>
#include <stdint.h>

#define KC   8      // mixture components
#define DIM  512    // obs dim
#define HID  512    // hidden
#define ACTN 1024   // actions
#define NS   64     // sequences
#define NT   128    // timesteps
#define NB   8192   // NS*NT
#define PB   4      // partial-lse blocks per row in GEMM2 (ACTN/256)

typedef __attribute__((ext_vector_type(8))) short short8;
typedef __attribute__((ext_vector_type(8))) unsigned short ushort8;
typedef __attribute__((ext_vector_type(4))) float floatx4;
typedef __attribute__((ext_vector_type(2))) float floatx2;
typedef __attribute__((ext_vector_type(4))) unsigned int uint4v;

__device__ inline float bf2f(unsigned short u) {
    return __uint_as_float(((unsigned int)u) << 16);
}
// cheap RNE f32->bf16 (no NaN handling needed for our data): 3 VALU ops
__device__ inline unsigned short f2bf_rne(float x) {
    unsigned int u = __float_as_uint(x);
    u += 0x7fffu + ((u >> 16) & 1u);
    return (unsigned short)(u >> 16);
}

// ---- fp8 e4m3fn encode/decode: HW packed converts (word-select must be
// a compile-time constant -> template parameter), manual fallback ----
__device__ inline unsigned char f2fp8_manual(float v) {
    unsigned int s = (__float_as_uint(v) >> 24) & 0x80u;
    float a = fabsf(v) * 0x1.0p-120f;
    unsigned int b = __float_as_uint(a);
    b += 0x7FFFFu + ((b >> 20) & 1u);
    unsigned int m = b >> 20;
    if (m > 0x7Eu) m = 0x7Eu;
    return (unsigned char)(s | m);
}
__device__ inline float fp82f_manual(unsigned int byte) {
    unsigned int bits = ((byte & 0x80u) << 24) | ((byte & 0x7Fu) << 20);
    return __uint_as_float(bits) * 0x1.0p+120f;
}
template <bool HI>
__device__ inline unsigned int pk_fp8(float a, float b, unsigned int old) {
#if __has_builtin(__builtin_amdgcn_cvt_pk_fp8_f32)
    return __builtin_amdgcn_cvt_pk_fp8_f32(a, b, old, HI);
#else
    unsigned int p = (unsigned int)f2fp8_manual(a) | ((unsigned int)f2fp8_manual(b) << 8);
    return HI ? ((old & 0x0000ffffu) | (p << 16)) : ((old & 0xffff0000u) | p);
#endif
}
template <bool HI>
__device__ inline floatx2 unpk_fp8(unsigned int src) {
#if __has_builtin(__builtin_amdgcn_cvt_pk_f32_fp8)
    return __builtin_amdgcn_cvt_pk_f32_fp8(src, HI);
#else
    unsigned int w = HI ? (src >> 16) : src;
    floatx2 r;
    r.x = fp82f_manual(w & 0xffu);
    r.y = fp82f_manual((w >> 8) & 0xffu);
    return r;
#endif
}

// async global->LDS DMA, 16B/lane. GLOBAL address is PER-LANE (pass g with
// lane*8 shorts folded in); LDS dest = wave-uniform base + lane*16.
__device__ inline void gload_lds16(const unsigned short* g, unsigned short* l) {
    __builtin_amdgcn_global_load_lds(
        (const __attribute__((address_space(1))) unsigned int*)g,
        (__attribute__((address_space(3))) unsigned int*)l,
        16, 0, 0);
}

// ================= BLK256 layout =================
// X_blk[z][dim/256][Kd/64][256 rows][8 slots][8 bf16], where the 16B slot s of
// row r holds logical k-chunk (s ^ (r&7))  -> ds_read_b128 of a column of rows
// lands on 8 distinct 16B slots per 8-row stripe (2-way = free).  Staging via
// global_load_lds is LINEAR (swizzle is pre-applied in the global layout).

// ---------------- fused prep: obs->BLK256 bf16, W1/W2 -> transposed BLK256 ----
__global__ __launch_bounds__(256) void prep_kernel(
    const float* __restrict__ obs, const float* __restrict__ W1,
    const float* __restrict__ W2,
    unsigned short* __restrict__ obs_bk, unsigned short* __restrict__ W1bk,
    unsigned short* __restrict__ W2bk)
{
    __shared__ float tile[64][65];
    int id = blockIdx.x;
    if (id < 128) {                       // ---- obs path: [B][D] -> BLK256
        int mg = id;
#pragma unroll
        for (int rep = 0; rep < 16; ++rep) {
            int idx = rep * 256 + threadIdx.x;   // 0..4095
            int row = mg * 64 + (idx >> 6);
            int c_all = idx & 63;
            int kt = c_all >> 3, c = c_all & 7;
            const float* p = obs + (size_t)row * DIM + c_all * 8;
            ushort8 u;
#pragma unroll
            for (int e = 0; e < 8; e++) u[e] = f2bf_rne(p[e]);
            size_t off = (((size_t)(row >> 8) * (DIM >> 6) + kt) << 14)
                       + ((size_t)(row & 255) << 6) + ((c ^ (row & 7)) << 3);
            *(ushort8*)(obs_bk + off) = u;
        }
        return;
    }
    // ---- weight transpose path: [z][R][C] -> [z][C/256][R/64][256][64] swz
    const float* src; unsigned short* dst; int R, C, xt, yt;
    if (id < 640) {                       // W1: 8 comps x (8 x 8) tiles
        int t = id - 128; int z = t >> 6; int rem = t & 63;
        xt = rem & 7; yt = rem >> 3;
        R = DIM; C = HID;
        src = W1 + (size_t)z * DIM * HID; dst = W1bk + (size_t)z * DIM * HID;
    } else {                              // W2: 8 comps x (16 x 8) tiles
        int t = id - 640; int z = t >> 7; int rem = t & 127;
        xt = rem & 15; yt = rem >> 4;
        R = HID; C = ACTN;
        src = W2 + (size_t)z * HID * ACTN; dst = W2bk + (size_t)z * HID * ACTN;
    }
    int h0 = xt * 64, d0 = yt * 64;
    int tx = threadIdx.x & 63, ty = threadIdx.x >> 6;
#pragma unroll
    for (int i = 0; i < 64; i += 4)
        tile[ty + i][tx] = src[(size_t)(d0 + ty + i) * C + h0 + tx];
    __syncthreads();
#pragma unroll
    for (int rep = 0; rep < 2; ++rep) {
        int idx  = rep * 256 + threadIdx.x;
        int h_l  = idx & 63;
        int dc   = idx >> 6;              // k-chunk within this 64-wide kt
        int rh   = h0 + h_l;              // output row (n index)
        ushort8 u;
#pragma unroll
        for (int e = 0; e < 8; e++) u[e] = f2bf_rne(tile[dc * 8 + e][h_l]);
        size_t off = (((size_t)(rh >> 8) * (R >> 6) + (d0 >> 6)) << 14)
                   + ((size_t)(rh & 255) << 6) + ((dc ^ (rh & 7)) << 3);
        *(ushort8*)(dst + off) = u;
    }
}

// ---------------- 256x256-tile 8-wave pipelined bf16 MFMA GEMM --------------
// 4 phases per K-tile (BK=64), 16 MFMA/phase/wave, raw s_barrier (no vmcnt
// drain), counted vmcnt(4) once per K-tile, setprio(1) around MFMA clusters.
// Safety: all ds_reads of K-tile T issue in phases 1-2 and are lgkmcnt(0)'d
// before phase-2's end barrier; phases 1-2 stage tile T+1's B halves (other
// buffer), phases 3-4 stage tile T+2's A halves (this buffer, reads done).
__global__ __launch_bounds__(512, 2) void gemm_blk_kernel(
    const unsigned short* __restrict__ Aall,
    const unsigned short* __restrict__ Ball,
    const float* __restrict__ biasall,
    void* __restrict__ Call,
    const int* __restrict__ actions,
    float* __restrict__ psum, float* __restrict__ palp,
    int M, int N, int Kd,
    long long zsA, long long zsB,
    int strideBias, long long strideCbytes,
    int do_relu, int do_blocked)
{
    // 2 K-tile buffers: bufA0[0,32K)B bufB0[32K,64K) bufA1[64K,96K) bufB1[96K,128K)
    // epilogue reuses as Cs[128][264] per half-pass
    __shared__ __align__(16) unsigned short S[65536];   // 128 KiB

    const int zb = blockIdx.z;
    const float* bias = biasall + (size_t)zb * strideBias;
    char* const Cbase = (char*)Call + (size_t)zb * strideCbytes;

    const int tid  = threadIdx.x;
    const int lane = tid & 63;
    const int w    = tid >> 6;      // 0..7
    const int wm   = w >> 2;        // 0..1  (row half)
    const int wn   = w & 3;         // 0..3  (col quarter)
    const int quad = lane >> 4;     // 0..3
    const int l16  = lane & 15;

    const int bm = blockIdx.x * 256;
    const int bn = blockIdx.y * 256;
    const int KT = Kd >> 6;         // #K-tiles == #64-chunk blocks in layout
    const int nk = KT;

    floatx4 acc[8][4];
#pragma unroll
    for (int i = 0; i < 8; i++)
#pragma unroll
        for (int j = 0; j < 4; j++)
            acc[i][j] = (floatx4){0.f, 0.f, 0.f, 0.f};

    // per-lane global staging bases (wave w stages rows [w*16,w*16+16) of each half)
    const unsigned short* srcA = Aall + (size_t)zb * zsA
        + (((size_t)(bm >> 8) * KT) << 14) + w * 1024 + lane * 8;
    const unsigned short* srcB = Ball + (size_t)zb * zsB
        + (((size_t)(bn >> 8) * KT) << 14) + w * 1024 + lane * 8;

    auto stageA = [&](int U, int HF) {
        const unsigned short* g = srcA + U * 16384 + HF * 8192;
        unsigned short* l = S + (U & 1) * 32768 + HF * 8192 + w * 1024;
        gload_lds16(g,       l);
        gload_lds16(g + 512, l + 512);
    };
    auto stageB = [&](int U, int HF) {
        const unsigned short* g = srcB + U * 16384 + HF * 8192;
        unsigned short* l = S + (U & 1) * 32768 + 16384 + HF * 8192 + w * 1024;
        gload_lds16(g,       l);
        gload_lds16(g + 512, l + 512);
    };

    // frag read offsets (ushort units, within a buffer); k-step1 = ^32
    const int swz  = (quad ^ (l16 & 7)) << 3;
    const int aoff0 = (wm * 128 + l16) * 64 + swz;
    const int boff0 = 16384 + (wn * 64 + l16) * 64 + swz;

    // ---- prologue: tile0 fully, tile1 A halves; wait tile0 landed ----
    stageA(0, 0); stageA(0, 1); stageB(0, 0); stageB(0, 1);
    if (nk > 1) { stageA(1, 0); stageA(1, 1); }
    if (nk > 1) asm volatile("s_waitcnt vmcnt(4)" ::: "memory");
    else        asm volatile("s_waitcnt vmcnt(0)" ::: "memory");
    __builtin_amdgcn_s_barrier();

    for (int T = 0; T < nk; ++T) {
        const int bo = (T & 1) * 32768;
        short8 a0[8], b0[4], a1[8], b1[4];
        // ---------- phase 1: read k0 frags; stage B-h0 of T+1 ----------
#pragma unroll
        for (int i = 0; i < 8; i++) a0[i] = *(const short8*)(S + bo + aoff0 + i * 1024);
#pragma unroll
        for (int j = 0; j < 4; j++) b0[j] = *(const short8*)(S + bo + boff0 + j * 1024);
        if (T + 1 < nk) stageB(T + 1, 0);
        __builtin_amdgcn_s_barrier();
        __builtin_amdgcn_s_setprio(1);
#pragma unroll
        for (int i = 0; i < 4; i++)
#pragma unroll
            for (int j = 0; j < 4; j++)
                acc[i][j] = __builtin_amdgcn_mfma_f32_16x16x32_bf16(a0[i], b0[j], acc[i][j], 0, 0, 0);
        __builtin_amdgcn_s_setprio(0);
        __builtin_amdgcn_s_barrier();
        // ---------- phase 2: read k1 frags; stage B-h1 of T+1 ----------
#pragma unroll
        for (int i = 0; i < 8; i++) a1[i] = *(const short8*)(S + bo + (aoff0 ^ 32) + i * 1024);
#pragma unroll
        for (int j = 0; j < 4; j++) b1[j] = *(const short8*)(S + bo + (boff0 ^ 32) + j * 1024);
        if (T + 1 < nk) stageB(T + 1, 1);
        __builtin_amdgcn_s_barrier();
        __builtin_amdgcn_s_setprio(1);
#pragma unroll
        for (int i = 4; i < 8; i++)
#pragma unroll
            for (int j = 0; j < 4; j++)
                acc[i][j] = __builtin_amdgcn_mfma_f32_16x16x32_bf16(a0[i], b0[j], acc[i][j], 0, 0, 0);
        __builtin_amdgcn_s_setprio(0);
        // all reads of this buffer must retire before phase-3 stages into it
        asm volatile("s_waitcnt lgkmcnt(0)" ::: "memory");
        __builtin_amdgcn_s_barrier();
        // ---------- phase 3: stage A-h0 of T+2 ----------
        if (T + 2 < nk) stageA(T + 2, 0);
        __builtin_amdgcn_s_barrier();
        __builtin_amdgcn_s_setprio(1);
#pragma unroll
        for (int i = 0; i < 4; i++)
#pragma unroll
            for (int j = 0; j < 4; j++)
                acc[i][j] = __builtin_amdgcn_mfma_f32_16x16x32_bf16(a1[i], b1[j], acc[i][j], 0, 0, 0);
        __builtin_amdgcn_s_setprio(0);
        __builtin_amdgcn_s_barrier();
        // ---------- phase 4: stage A-h1 of T+2; counted vmcnt ----------
        if (T + 2 < nk) stageA(T + 2, 1);
        __builtin_amdgcn_s_barrier();
        __builtin_amdgcn_s_setprio(1);
#pragma unroll
        for (int i = 4; i < 8; i++)
#pragma unroll
            for (int j = 0; j < 4; j++)
                acc[i][j] = __builtin_amdgcn_mfma_f32_16x16x32_bf16(a1[i], b1[j], acc[i][j], 0, 0, 0);
        __builtin_amdgcn_s_setprio(0);
        if (T < nk - 2)       asm volatile("s_waitcnt vmcnt(4)" ::: "memory");
        else if (T == nk - 2) asm volatile("s_waitcnt vmcnt(0)" ::: "memory");
        __builtin_amdgcn_s_barrier();
    }

    // ---- epilogue: two 128-row passes through Cs[128][264] (reuses staging LDS)
    // C/D layout (verified): col = lane&15, row = quad*4 + reg.
    for (int h = 0; h < 2; ++h) {
        if (wm == h) {
#pragma unroll
            for (int j = 0; j < 4; j++) {
                int col = wn * 64 + j * 16 + l16;
                float bv = bias[bn + col];
#pragma unroll
                for (int i = 0; i < 8; i++) {
                    int r0 = i * 16 + quad * 4;
#pragma unroll
                    for (int r = 0; r < 4; r++) {
                        float v = acc[i][j][r] + bv;
                        if (do_relu) v = fmaxf(v, 0.f);
                        S[(r0 + r) * 264 + col] = f2bf_rne(v);
                    }
                }
            }
        }
        __builtin_amdgcn_s_barrier();
        if (do_blocked) {
            // ---- BLK256-swizzled bf16 store (= next GEMM's A layout) ----
            unsigned short* Cb16 = (unsigned short*)Cbase;
            const int KTo = N >> 6;
#pragma unroll
            for (int rep = 0; rep < 8; ++rep) {
                int idx  = rep * 512 + tid;      // 0..4095
                int r_l  = idx >> 5;             // 0..127
                int s5   = idx & 31;
                int kt_l = s5 >> 3, st = s5 & 7;
                int r    = h * 128 + r_l;        // row within 256-tile
                int c    = st ^ (r & 7);         // logical chunk at phys slot st
                ushort8 u = *(const ushort8*)&S[r_l * 264 + kt_l * 64 + c * 8];
                size_t off = (((size_t)(bm >> 8) * KTo + (bn >> 6) + kt_l) << 14)
                           + ((size_t)r << 6) + (st << 3);
                *(ushort8*)(Cb16 + off) = u;
            }
        } else {
            // ---- row-major fp8 store + fused exp-sum / action gather ----
            unsigned char* Cb8 = (unsigned char*)Cbase;
            const int r_l = tid >> 2;            // 0..127
            const int ch  = (tid & 3) * 64;      // 4 threads/row, 64 cols each
            const int r   = h * 128 + r_l;
            unsigned char* crow = Cb8 + (size_t)(bm + r) * N + bn + ch;
            float ssum = 0.f;
#pragma unroll
            for (int g = 0; g < 4; g++) {        // 16 els -> one 16B store
                ushort8 u0 = *(const ushort8*)&S[r_l * 264 + ch + 16 * g];
                ushort8 u1 = *(const ushort8*)&S[r_l * 264 + ch + 16 * g + 8];
                float v[16];
#pragma unroll
                for (int e = 0; e < 8; e++) { v[e] = bf2f(u0[e]); v[8 + e] = bf2f(u1[e]); }
#pragma unroll
                for (int e = 0; e < 16; e++) ssum += __expf(v[e]);
                uint4v pk;
                pk.x = pk_fp8<true>(v[2],  v[3],  pk_fp8<false>(v[0],  v[1],  0u));
                pk.y = pk_fp8<true>(v[6],  v[7],  pk_fp8<false>(v[4],  v[5],  0u));
                pk.z = pk_fp8<true>(v[10], v[11], pk_fp8<false>(v[8],  v[9],  0u));
                pk.w = pk_fp8<true>(v[14], v[15], pk_fp8<false>(v[12], v[13], 0u));
                *(uint4v*)(crow + 16 * g) = pk;
            }
            float t1 = ssum + __shfl_xor(ssum, 1);
            float stot = t1 + __shfl_xor(t1, 2);
            size_t kb = (size_t)zb * M + bm + r;   // M == NB for GEMM2
            if ((tid & 3) == 0)
                psum[kb * PB + blockIdx.y] = stot;
            int a_act = actions[bm + r];
            int rel = a_act - bn;
            if (rel >= ch && rel < ch + 64)
                palp[kb] = bf2f(S[r_l * 264 + rel]);   // bf16-accurate action logit
        }
        __builtin_amdgcn_s_barrier();
    }
}

// ---------------- per-sequence: lse-finish + scan + mixture posterior ----------------
__global__ __launch_bounds__(128) void mix_kernel(
    const float* __restrict__ palp,   // [K][B]  raw action logit (bf16 acc)
    const float* __restrict__ psum,   // [K][B][PB]  raw exp-sums
    const float* __restrict__ start,  // [S][K]
    float* __restrict__ w,            // [K][B]  = mix - lse
    float* __restrict__ fmix)         // [S][K]
{
    __shared__ float buf[2][NT][9];
    int s = blockIdx.x, t = threadIdx.x;
    int b = s * NT + t;

    float a[KC], lsev[KC];
#pragma unroll
    for (int k = 0; k < KC; k++) {
        size_t kb = (size_t)k * NB + b;
        const float* ps = psum + kb * PB;
        float Ssum = 0.f;
#pragma unroll
        for (int p = 0; p < PB; p++) Ssum += ps[p];
        float l = __logf(Ssum);
        lsev[k] = l;
        a[k] = palp[kb] - l;          // action logprob
    }

#pragma unroll
    for (int k = 0; k < KC; k++) buf[0][t][k] = a[k];
    int p = 0;
    for (int off = 1; off < NT; off <<= 1) {
        __syncthreads();
#pragma unroll
        for (int k = 0; k < KC; k++) {
            float x = buf[p][t][k];
            if (t >= off) x += buf[p][t - off][k];
            buf[1 - p][t][k] = x;
        }
        p ^= 1;
    }
    __syncthreads();
    float st[KC], e[KC];
#pragma unroll
    for (int k = 0; k < KC; k++) st[k] = start[s * KC + k];
#pragma unroll
    for (int k = 0; k < KC; k++) e[k] = st[k] + buf[p][t][k] - a[k];  // exclusive cumsum
    float m = e[0];
#pragma unroll
    for (int k = 1; k < KC; k++) m = fmaxf(m, e[k]);
    float sum = 0.f;
#pragma unroll
    for (int k = 0; k < KC; k++) sum += __expf(e[k] - m);
    float l = m + __logf(sum);
#pragma unroll
    for (int k = 0; k < KC; k++)
        w[(size_t)k * NB + b] = (e[k] - l) - lsev[k];

    if (t == NT - 1) {
        float f[KC];
#pragma unroll
        for (int k = 0; k < KC; k++) f[k] = st[k] + buf[p][t][k];
        float m2 = f[0];
#pragma unroll
        for (int k = 1; k < KC; k++) m2 = fmaxf(m2, f[k]);
        float s2 = 0.f;
#pragma unroll
        for (int k = 0; k < KC; k++) s2 += __expf(f[k] - m2);
        float l2 = m2 + __logf(s2);
#pragma unroll
        for (int k = 0; k < KC; k++) fmix[s * KC + k] = f[k] - l2;
    }
}

// ---------------- final combine: out[b,a] = LSE_k(logit8[k,b,a] + w[k,b]) ----------------
__global__ __launch_bounds__(256) void combine_kernel(
    const unsigned char* __restrict__ logits8,  // [K][B][A] fp8 e4m3
    const float* __restrict__ w,                // [K][B]
    float* __restrict__ out)                    // [B][A]
{
    int b  = blockIdx.x * 2 + (threadIdx.x >> 7);
    int a0 = (threadIdx.x & 127) * 8;
    float x[KC][8];
#pragma unroll
    for (int k = 0; k < KC; k++) {
        float wv = w[(size_t)k * NB + b];
        uint2 q = *(const uint2*)(logits8 + ((size_t)k * NB + b) * ACTN + a0);
        floatx2 p01 = unpk_fp8<false>(q.x), p23 = unpk_fp8<true>(q.x);
        floatx2 p45 = unpk_fp8<false>(q.y), p67 = unpk_fp8<true>(q.y);
        x[k][0] = p01.x + wv; x[k][1] = p01.y + wv;
        x[k][2] = p23.x + wv; x[k][3] = p23.y + wv;
        x[k][4] = p45.x + wv; x[k][5] = p45.y + wv;
        x[k][6] = p67.x + wv; x[k][7] = p67.y + wv;
    }
    float* op = out + (size_t)b * ACTN + a0;
#pragma unroll
    for (int j = 0; j < 8; j++) {
        float m = x[0][j];
#pragma unroll
        for (int k = 1; k < KC; k++) m = fmaxf(m, x[k][j]);
        float s = 0.f;
#pragma unroll
        for (int k = 0; k < KC; k++) s += __expf(x[k][j] - m);
        op[j] = m + __logf(s);
    }
}

extern "C" void kernel_launch(void* const* d_in, const int* in_sizes, int n_in,
                              void* d_out, int out_size, void* d_ws, size_t ws_size,
                              hipStream_t stream)
{
    const float* obs     = (const float*)d_in[0];
    const int*   actions = (const int*)d_in[1];
    const float* start   = (const float*)d_in[2];
    const float* W1      = (const float*)d_in[3];
    const float* b1      = (const float*)d_in[4];
    const float* W2      = (const float*)d_in[5];
    const float* b2      = (const float*)d_in[6];
    // d_in[7] = seq_len (compile-time NT)

    char* ws = (char*)d_ws;
    unsigned short* obs_bk  = (unsigned short*)ws; ws += (size_t)NB * DIM * 2;        // 8 MB
    unsigned short* W1bk    = (unsigned short*)ws; ws += (size_t)KC * HID * DIM * 2;  // 4 MB
    unsigned short* W2bk    = (unsigned short*)ws; ws += (size_t)KC * ACTN * HID * 2; // 8 MB
    unsigned short* hbuf    = (unsigned short*)ws; ws += (size_t)KC * NB * HID * 2;   // 64 MB
    unsigned char*  logits8 = (unsigned char*)ws;  ws += (size_t)KC * NB * ACTN;      // 64 MB
    float* wbuf = (float*)ws; ws += (size_t)KC * NB * 4;                              // 256 KB
    float* psum = (float*)ws; ws += (size_t)KC * NB * PB * 4;                         // 1 MB
    float* palp = (float*)ws; ws += (size_t)KC * NB * 4;                              // 256 KB

    float* out  = (float*)d_out;
    float* fmix = out + (size_t)NB * ACTN;

    // 1. fused prep: obs + W1 + W2 -> BLK256 pre-swizzled bf16
    prep_kernel<<<1664, 256, 0, stream>>>(obs, W1, W2, obs_bk, W1bk, W2bk);

    // 2. h = relu(obs @ W1[k] + b1[k]) -> BLK256 bf16 (zsA=0: obs shared!)
    gemm_blk_kernel<<<dim3(NB / 256, HID / 256, KC), 512, 0, stream>>>(
        obs_bk, W1bk, b1, hbuf, actions, psum, palp,
        NB, HID, DIM,
        0LL, (long long)HID * DIM,
        HID, (long long)NB * HID * 2, 1, 1);

    // 3. logits = h @ W2[k] + b2[k] -> fp8 [K][B][A] + fused exp-sum + gather
    gemm_blk_kernel<<<dim3(NB / 256, ACTN / 256, KC), 512, 0, stream>>>(
        hbuf, W2bk, b2, logits8, actions, psum, palp,
        NB, ACTN, HID,
        (long long)NB * HID, (long long)ACTN * HID,
        ACTN, (long long)NB * ACTN, 0, 0);

    // 4. per-sequence: lse-finish + cumsum scan -> mixture weights + final mixture logprobs
    mix_kernel<<<NS, NT, 0, stream>>>(palp, psum, start, wbuf, fmix);

    // 5. combine over components
    combine_kernel<<<NB / 2, 256, 0, stream>>>(logits8, wbuf, out);
}